// Round 11
// baseline (698.271 us; speedup 1.0000x reference)
//
#include <hip/hip_runtime.h>
#include <cmath>
#include <cstdint>

#pragma clang fp contract(off)

#define B_ 2
#define N_ 65536
#define M_ 128
#define K_ 2048
#define S_ 6
#define NBLK 256          /* classify/compact blocks per batch */
#define CT 256            /* classify/compact threads per block */
#define WCAP 4096         /* single-wave path capacity (64 slots/lane max) */

#define PI_F 3.14159265358979323846f
#define SS_F 1.0471975511965976f   /* (float)(2.0*pi/6) */

// ---- DPP reduce helpers (VALU latency; accumulate toward lane 63) ----
// f32 max with own-value fill (identity-safe for any data).
__device__ __forceinline__ float wave_max_f32_dpp(float v) {
#define STEP(CTRL)                                                              \
    {                                                                           \
        int o = __builtin_amdgcn_update_dpp(__float_as_int(v), __float_as_int(v), \
                                            CTRL, 0xf, 0xf, false);             \
        v = fmaxf(v, __int_as_float(o));                                        \
    }
    STEP(0x111) STEP(0x112) STEP(0x114) STEP(0x118) STEP(0x142) STEP(0x143)
#undef STEP
    return v;
}
// u32 min with own-value fill.
__device__ __forceinline__ unsigned wave_min_u32_dpp(unsigned v) {
#define STEP(CTRL)                                                              \
    {                                                                           \
        unsigned o = (unsigned)__builtin_amdgcn_update_dpp((int)v, (int)v,      \
                                            CTRL, 0xf, 0xf, false);             \
        v = (o < v) ? o : v;                                                    \
    }
    STEP(0x111) STEP(0x112) STEP(0x114) STEP(0x118) STEP(0x142) STEP(0x143)
#undef STEP
    return v;
}
// 64-bit key max (fallback path).
__device__ __forceinline__ unsigned long long wave_max_u64_dpp(unsigned long long key) {
#define DPP_STEP(CTRL)                                                          \
    {                                                                           \
        unsigned lo = (unsigned)key, hi = (unsigned)(key >> 32);                \
        unsigned olo = (unsigned)__builtin_amdgcn_update_dpp(0, (int)lo, CTRL, 0xf, 0xf, true); \
        unsigned ohi = (unsigned)__builtin_amdgcn_update_dpp(0, (int)hi, CTRL, 0xf, 0xf, true); \
        unsigned long long o = ((unsigned long long)ohi << 32) | olo;           \
        if (o > key) key = o;                                                   \
    }
    DPP_STEP(0x111) DPP_STEP(0x112) DPP_STEP(0x114)
    DPP_STEP(0x118) DPP_STEP(0x142) DPP_STEP(0x143)
#undef DPP_STEP
    return key;
}

// ------------------------------------------------------------ classify ----
__global__ __launch_bounds__(CT)
void k_classify(const float* __restrict__ points, const float* __restrict__ rois,
                int* __restrict__ sec_id, int* __restrict__ blkcnt) {
    __shared__ float4 sroi[M_];
    __shared__ int lc[8];
    int blk = blockIdx.x;
    int gid = blk * CT + threadIdx.x;
    int b = gid >> 16;                       // N_ = 65536
    if (threadIdx.x < M_) {
        const float* r = rois + ((size_t)b * M_ + threadIdx.x) * 7;
        float cz = r[2] + r[5] * 0.5f;       // geometric center
        float hx = r[3] * 0.5f, hy = r[4] * 0.5f, hz = r[5] * 0.5f;
        sroi[threadIdx.x] = make_float4(r[0], r[1], cz, sqrtf((hx*hx + hy*hy) + hz*hz));
    }
    if (threadIdx.x < 8) lc[threadIdx.x] = 0;
    __syncthreads();

    const float* p = points + (size_t)gid * 3;
    float px = p[0], py = p[1], pz = p[2];
    float best = 1e30f; int bi = 0;
    for (int m = 0; m < M_; m++) {
        float4 c = sroi[m];
        float dx = px - c.x, dy = py - c.y, dz = pz - c.z;
        float d = sqrtf((dx*dx + dy*dy) + dz*dz);
        if (d < best) { best = d; bi = m; }  // strict < : first argmin
    }
    bool valid = best < (sroi[bi].w + 1.6f);

    float a = atan2f(py, px) + PI_F;
    float fs = floorf(a / SS_F);
    fs = fminf(fmaxf(fs, 0.0f), 6.0f);
    int sec = (int)fs;

    sec_id[gid] = valid ? sec : -1;
    if (valid) atomicAdd(&lc[sec], 1);
    __syncthreads();
    if (threadIdx.x < 8) blkcnt[blk * 8 + threadIdx.x] = lc[threadIdx.x];
}

// ---------------------------------------------------------------- plan ----
__global__ void k_plan(const int* __restrict__ blkcnt, int* __restrict__ bbase,
                       int* __restrict__ cnt, int* __restrict__ offv,
                       int* __restrict__ n_needed, int* __restrict__ sec_base,
                       int* __restrict__ s_total) {
    __shared__ int scnt[2][8];
    int t = threadIdx.x;
    if (t < 16) scnt[t >> 3][t & 7] = 0;
    __syncthreads();
    if (t < 14) {
        int b = t / 7, s = t % 7;
        int run = 0;
        #pragma unroll 8
        for (int j = 0; j < NBLK; j++) {
            int blk = b * NBLK + j;
            int c = blkcnt[blk * 8 + s];
            if (s < 6) bbase[blk * 6 + s] = run;
            run += c;
        }
        scnt[b][s] = run;
        cnt[b * 8 + s] = run;
    }
    __syncthreads();
    if (t < B_) {
        int b = t;
        int total = 0;
        for (int s = 0; s < 7; s++) total += scnt[b][s];
        if (total < 1) total = 1;
        int sb = 0, snk = 0;
        for (int s = 0; s < 6; s++) {
            int cs = scnt[b][s];
            int nk = (int)ceilf((float)cs * 2048.0f / (float)total);  // f32 semantics
            if (nk > cs) nk = cs;
            offv[b * 6 + s] = snk;
            int need = 0;
            if (snk < K_) { need = K_ - snk; if (need > nk) need = nk; }
            n_needed[b * 6 + s] = need;
            sec_base[b * 6 + s] = sb;
            sb += cs; snk += nk;
        }
        s_total[b] = (snk < 1) ? 1 : snk;
    }
}

// ------------------------------------------------------------- compact ----
__global__ __launch_bounds__(CT)
void k_compact(const float* __restrict__ points, const int* __restrict__ sec_id,
               const int* __restrict__ sec_base, const int* __restrict__ bbase,
               int* __restrict__ comp_idx, float4* __restrict__ comp_xyz) {
    __shared__ int lc[4 * 6];
    __shared__ int sbase[6], blkb[6];
    int blk = blockIdx.x;
    int b = blk >> 8;                         // NBLK = 256 blocks per batch
    int tid = threadIdx.x, lane = tid & 63, wid = tid >> 6;
    if (tid < 6) sbase[tid] = sec_base[b * 6 + tid];
    else if (tid >= 64 && tid < 70) blkb[tid - 64] = bbase[blk * 6 + (tid - 64)];
    int gid = blk * CT + tid;
    int sec = sec_id[gid];
    unsigned long long mymask = 0;
    for (int s = 0; s < 6; s++) {
        unsigned long long m = __ballot(sec == s);
        if (sec == s) mymask = m;
        if (lane == 0) lc[wid * 6 + s] = __popcll(m);
    }
    __syncthreads();
    if (sec >= 0 && sec < 6) {
        int woff = 0;
        for (int w = 0; w < wid; w++) woff += lc[w * 6 + sec];
        int rank = __popcll(mymask & ((1ull << lane) - 1ull));
        int addr = b * N_ + sbase[sec] + blkb[sec] + woff + rank;
        const float* p = points + (size_t)gid * 3;
        comp_idx[addr] = gid & (N_ - 1);
        comp_xyz[addr] = make_float4(p[0], p[1], p[2], 0.0f);
    }
}

// ------------------------------------------- fps single-wave (cs<=4096) ----
// barrier-free: dmin+xyz in registers, winner value via 6-step f32-max DPP,
// winner index via 6-step u32-min DPP among max-achieving lanes, winner xyz
// via one uniform-address ds_read from the wave-private mirror. lane0's buf
// store queues in vmcnt (never drained in-loop).
template<int R>
__device__ __forceinline__
void fps_wave(const float4* __restrict__ cxyz, float4* __restrict__ sxyz,
              int cs, int need, int base, int off, int* __restrict__ buf,
              int lane) {
    float px[R], py[R], pz[R], dmv[R];
    #pragma unroll
    for (int r = 0; r < R; r++) {
        int i = r * 64 + lane;
        if (i < cs) {
            float4 q = cxyz[i];
            sxyz[i] = q;
            px[r] = q.x; py[r] = q.y; pz[r] = q.z;
            dmv[r] = 1e10f;
        } else {
            px[r] = 0.0f; py[r] = 0.0f; pz[r] = 0.0f;
            dmv[r] = -1e30f;                 // pad: always loses (bv starts -1)
        }
    }
    if (lane == 0) buf[off] = base;          // first pick = first point
    if (need == 1) return;
    float4 f0 = cxyz[0];
    float lx = f0.x, ly = f0.y, lz = f0.z;

    #pragma unroll 1
    for (int k = 1; k < need; k++) {
        float bv = -1.0f; int bi = 0;
        #pragma unroll
        for (int r = 0; r < R; r++) {
            float dx = px[r] - lx, dy = py[r] - ly, dz = pz[r] - lz;
            float d = (dx*dx + dy*dy) + dz*dz;        // contract off
            float nd = fminf(dmv[r], d);
            dmv[r] = nd;
            if (nd > bv) { bv = nd; bi = r * 64 + lane; }  // strict >: first r
        }
        float mv = wave_max_f32_dpp(bv);
        float maxv = __int_as_float(__builtin_amdgcn_readlane(__float_as_int(mv), 63));
        unsigned idx = (bv == maxv) ? (unsigned)bi : 0xFFFFFFFFu;
        idx = wave_min_u32_dpp(idx);
        int wi = (int)(unsigned)__builtin_amdgcn_readlane((int)idx, 63);
        if (lane == 0) buf[off + k] = base + wi;   // queued store, no drain
        float4 n4 = sxyz[wi];                // uniform-address LDS broadcast
        lx = n4.x; ly = n4.y; lz = n4.z;
    }
}

// launch_bounds(64, 1): ONE wave min per EU -> full ~512 VGPR budget.
// (Default allocator targets ~4 waves/SIMD and caps at 128 VGPR -> spills the
// point arrays to scratch; R10 measured 736 KB scratch writes on the chain.)
__global__ __launch_bounds__(64, 1)
void k_fps_wave(const int* __restrict__ cnt, const int* __restrict__ sec_base,
                const int* __restrict__ offv, const int* __restrict__ n_needed,
                const float4* __restrict__ comp_xyz, int* __restrict__ buf) {
    __shared__ float4 sxyz[WCAP];            // 64 KB
    int b = blockIdx.x / S_, s = blockIdx.x % S_;
    int need = n_needed[b * 6 + s];
    if (need <= 0) return;
    int cs = cnt[b * 8 + s];
    if (cs > WCAP) return;                   // k_fps_big handles
    int base = b * N_ + sec_base[b * 6 + s];
    const float4* cxyz = comp_xyz + base;
    int off = b * K_ + offv[b * 6 + s];
    int lane = threadIdx.x;

    if      (cs <=  512) fps_wave< 8>(cxyz, sxyz, cs, need, base, off, buf, lane);
    else if (cs <= 1024) fps_wave<16>(cxyz, sxyz, cs, need, base, off, buf, lane);
    else if (cs <= 1536) fps_wave<24>(cxyz, sxyz, cs, need, base, off, buf, lane);
    else if (cs <= 2048) fps_wave<32>(cxyz, sxyz, cs, need, base, off, buf, lane);
    else if (cs <= 2560) fps_wave<40>(cxyz, sxyz, cs, need, base, off, buf, lane);
    else if (cs <= 3072) fps_wave<48>(cxyz, sxyz, cs, need, base, off, buf, lane);
    else if (cs <= 3584) fps_wave<56>(cxyz, sxyz, cs, need, base, off, buf, lane);
    else                 fps_wave<64>(cxyz, sxyz, cs, need, base, off, buf, lane);
}

// --------------------------------------- fps fallback (cs>4096, unlikely) ----
__global__ __launch_bounds__(256, 3)
void k_fps_big(const int* __restrict__ cnt, const int* __restrict__ sec_base,
               const int* __restrict__ offv, const int* __restrict__ n_needed,
               const float4* __restrict__ comp_xyz,
               float* __restrict__ dmin_g, int* __restrict__ buf) {
    __shared__ int pick[K_];
    __shared__ unsigned long long skey[2][4];
    int b = blockIdx.x / S_, s = blockIdx.x % S_;
    int need = n_needed[b * 6 + s];
    if (need <= 0) return;
    int cs = cnt[b * 8 + s];
    if (cs <= WCAP) return;                  // k_fps_wave handled
    int base = b * N_ + sec_base[b * 6 + s];
    const float4* cxyz = comp_xyz + base;
    int off = b * K_ + offv[b * 6 + s];
    int tid = threadIdx.x, lane = tid & 63, wid = tid >> 6;

    float* dm = dmin_g + base;
    if (tid == 0) pick[0] = 0;
    __syncthreads();
    float4 f0 = cxyz[0];
    float lx = f0.x, ly = f0.y, lz = f0.z;
    #pragma unroll 1
    for (int k = 1; k < need; k++) {
        unsigned long long key = 0;
        #pragma unroll 1
        for (int i = tid; i < cs; i += 256) {
            float4 q = cxyz[i];
            float dx = q.x - lx, dy = q.y - ly, dz = q.z - lz;
            float d = (dx*dx + dy*dy) + dz*dz;
            float prev = (k == 1) ? 1e10f : dm[i];
            float nd = fminf(prev, d);
            dm[i] = nd;
            unsigned long long kk =
                ((unsigned long long)__float_as_uint(nd) << 32) | (unsigned)(~(unsigned)i);
            if (kk > key) key = kk;
        }
        key = wave_max_u64_dpp(key);
        int par = k & 1;
        if (lane == 63) skey[par][wid] = key;
        __syncthreads();
        unsigned long long bk = skey[par][0];
        if (skey[par][1] > bk) bk = skey[par][1];
        if (skey[par][2] > bk) bk = skey[par][2];
        if (skey[par][3] > bk) bk = skey[par][3];
        int bix = (int)(~(unsigned)(bk & 0xFFFFFFFFull));
        if (tid == 0) pick[k] = bix;
        float4 n4 = cxyz[bix];
        lx = n4.x; ly = n4.y; lz = n4.z;
    }
    __syncthreads();
    #pragma unroll 1
    for (int i = tid; i < need; i += 256)
        buf[off + i] = base + pick[i];
}

// ----------------------------------------------------------------- out ----
__global__ void k_out(const float* __restrict__ points, const int* __restrict__ buf,
                      const int* __restrict__ comp_idx, const int* __restrict__ s_total,
                      float* __restrict__ out) {
    int i = blockIdx.x * 256 + threadIdx.x;
    if (i >= B_ * K_) return;
    int b = i / K_, j = i % K_;
    int st = s_total[b];
    int g = buf[b * K_ + (j % st)];          // compacted global slot
    int idx = comp_idx[g];                   // original point index
    const float* p = points + ((size_t)b * N_ + idx) * 3;
    float* o = out + (size_t)i * 3;
    o[0] = p[0]; o[1] = p[1]; o[2] = p[2];
}

// -------------------------------------------------------------- launch ----
extern "C" void kernel_launch(void* const* d_in, const int* in_sizes, int n_in,
                              void* d_out, int out_size, void* d_ws, size_t ws_size,
                              hipStream_t stream) {
    const float* points = (const float*)d_in[0];   // [B,N,3]
    const float* rois   = (const float*)d_in[1];   // [B,M,7]
    float* out = (float*)d_out;                    // [B,K,3]

    char* w = (char*)d_ws;
    auto carve = [&](size_t bytes) -> char* {
        char* p = w; w += (bytes + 255) & ~(size_t)255; return p;
    };
    int*    sec_id   = (int*)   carve((size_t)B_ * N_ * sizeof(int));
    int*    blkcnt   = (int*)   carve((size_t)B_ * NBLK * 8 * sizeof(int));
    int*    bbase    = (int*)   carve((size_t)B_ * NBLK * 6 * sizeof(int));
    int*    cnt      = (int*)   carve((size_t)B_ * 8 * sizeof(int));
    int*    offv     = (int*)   carve((size_t)B_ * 6 * sizeof(int));
    int*    n_needed = (int*)   carve((size_t)B_ * 6 * sizeof(int));
    int*    sec_base = (int*)   carve((size_t)B_ * 6 * sizeof(int));
    int*    s_total  = (int*)   carve((size_t)B_ * sizeof(int));
    int*    buf      = (int*)   carve((size_t)B_ * K_ * sizeof(int));
    int*    comp_idx = (int*)   carve((size_t)B_ * N_ * sizeof(int));
    float4* comp_xyz = (float4*)carve((size_t)B_ * N_ * sizeof(float4));
    float*  dmin_g   = (float*) carve((size_t)B_ * N_ * sizeof(float));

    hipLaunchKernelGGL(k_classify, dim3(B_ * NBLK), dim3(CT), 0, stream,
                       points, rois, sec_id, blkcnt);
    hipLaunchKernelGGL(k_plan, dim3(1), dim3(64), 0, stream,
                       blkcnt, bbase, cnt, offv, n_needed, sec_base, s_total);
    hipLaunchKernelGGL(k_compact, dim3(B_ * NBLK), dim3(CT), 0, stream,
                       points, sec_id, sec_base, bbase, comp_idx, comp_xyz);
    hipLaunchKernelGGL(k_fps_wave, dim3(B_ * S_), dim3(64), 0, stream,
                       cnt, sec_base, offv, n_needed, comp_xyz, buf);
    hipLaunchKernelGGL(k_fps_big, dim3(B_ * S_), dim3(256), 0, stream,
                       cnt, sec_base, offv, n_needed, comp_xyz, dmin_g, buf);
    hipLaunchKernelGGL(k_out, dim3((B_ * K_ + 255) / 256), dim3(256), 0, stream,
                       points, buf, comp_idx, s_total, out);
}

// Round 12
// 519.343 us; speedup vs baseline: 1.3445x; 1.3445x over previous
//
#include <hip/hip_runtime.h>
#include <cmath>
#include <cstdint>

#pragma clang fp contract(off)

#define B_ 2
#define N_ 65536
#define M_ 128
#define K_ 2048
#define S_ 6
#define NBLK 256          /* classify/compact blocks per batch */
#define CT 256            /* classify/compact threads per block */
#define FPS_T 256
#define NW 4              /* FPS_T / 64 waves */
#define RMAX 16           /* 4-wave path slots (cap 4096) */
#define CAP (FPS_T * RMAX)
#define SW_CAP 1024       /* single-wave sub-path cap */

#define PI_F 3.14159265358979323846f
#define SS_F 1.0471975511965976f   /* (float)(2.0*pi/6) */

// 64-bit key max via DPP (VALU latency). Lane 63 holds result. Identity 0.
__device__ __forceinline__ unsigned long long wave_max_u64_dpp(unsigned long long key) {
#define DPP_STEP(CTRL)                                                          \
    {                                                                           \
        unsigned lo = (unsigned)key, hi = (unsigned)(key >> 32);                \
        unsigned olo = (unsigned)__builtin_amdgcn_update_dpp(0, (int)lo, CTRL, 0xf, 0xf, true); \
        unsigned ohi = (unsigned)__builtin_amdgcn_update_dpp(0, (int)hi, CTRL, 0xf, 0xf, true); \
        unsigned long long o = ((unsigned long long)ohi << 32) | olo;           \
        if (o > key) key = o;                                                   \
    }
    DPP_STEP(0x111) DPP_STEP(0x112) DPP_STEP(0x114)
    DPP_STEP(0x118) DPP_STEP(0x142) DPP_STEP(0x143)
#undef DPP_STEP
    return key;
}
// f32 max, own-value fill (single-wave path).
__device__ __forceinline__ float wave_max_f32_dpp(float v) {
#define STEP(CTRL)                                                              \
    {                                                                           \
        int o = __builtin_amdgcn_update_dpp(__float_as_int(v), __float_as_int(v), \
                                            CTRL, 0xf, 0xf, false);             \
        v = fmaxf(v, __int_as_float(o));                                        \
    }
    STEP(0x111) STEP(0x112) STEP(0x114) STEP(0x118) STEP(0x142) STEP(0x143)
#undef STEP
    return v;
}
// u32 min, own-value fill (single-wave path).
__device__ __forceinline__ unsigned wave_min_u32_dpp(unsigned v) {
#define STEP(CTRL)                                                              \
    {                                                                           \
        unsigned o = (unsigned)__builtin_amdgcn_update_dpp((int)v, (int)v,      \
                                            CTRL, 0xf, 0xf, false);             \
        v = (o < v) ? o : v;                                                    \
    }
    STEP(0x111) STEP(0x112) STEP(0x114) STEP(0x118) STEP(0x142) STEP(0x143)
#undef STEP
    return v;
}

// ------------------------------------------------------------ classify ----
__global__ __launch_bounds__(CT)
void k_classify(const float* __restrict__ points, const float* __restrict__ rois,
                int* __restrict__ sec_id, int* __restrict__ blkcnt) {
    __shared__ float4 sroi[M_];
    __shared__ int lc[8];
    int blk = blockIdx.x;
    int gid = blk * CT + threadIdx.x;
    int b = gid >> 16;                       // N_ = 65536
    if (threadIdx.x < M_) {
        const float* r = rois + ((size_t)b * M_ + threadIdx.x) * 7;
        float cz = r[2] + r[5] * 0.5f;       // geometric center
        float hx = r[3] * 0.5f, hy = r[4] * 0.5f, hz = r[5] * 0.5f;
        sroi[threadIdx.x] = make_float4(r[0], r[1], cz, sqrtf((hx*hx + hy*hy) + hz*hz));
    }
    if (threadIdx.x < 8) lc[threadIdx.x] = 0;
    __syncthreads();

    const float* p = points + (size_t)gid * 3;
    float px = p[0], py = p[1], pz = p[2];
    float best = 1e30f; int bi = 0;
    for (int m = 0; m < M_; m++) {
        float4 c = sroi[m];
        float dx = px - c.x, dy = py - c.y, dz = pz - c.z;
        float d = sqrtf((dx*dx + dy*dy) + dz*dz);
        if (d < best) { best = d; bi = m; }  // strict < : first argmin
    }
    bool valid = best < (sroi[bi].w + 1.6f);

    float a = atan2f(py, px) + PI_F;
    float fs = floorf(a / SS_F);
    fs = fminf(fmaxf(fs, 0.0f), 6.0f);
    int sec = (int)fs;

    sec_id[gid] = valid ? sec : -1;
    if (valid) atomicAdd(&lc[sec], 1);
    __syncthreads();
    if (threadIdx.x < 8) blkcnt[blk * 8 + threadIdx.x] = lc[threadIdx.x];
}

// ---------------------------------------------------------------- plan ----
__global__ void k_plan(const int* __restrict__ blkcnt, int* __restrict__ bbase,
                       int* __restrict__ cnt, int* __restrict__ offv,
                       int* __restrict__ n_needed, int* __restrict__ sec_base,
                       int* __restrict__ s_total) {
    __shared__ int scnt[2][8];
    int t = threadIdx.x;
    if (t < 16) scnt[t >> 3][t & 7] = 0;
    __syncthreads();
    if (t < 14) {
        int b = t / 7, s = t % 7;
        int run = 0;
        #pragma unroll 8
        for (int j = 0; j < NBLK; j++) {
            int blk = b * NBLK + j;
            int c = blkcnt[blk * 8 + s];
            if (s < 6) bbase[blk * 6 + s] = run;
            run += c;
        }
        scnt[b][s] = run;
        cnt[b * 8 + s] = run;
    }
    __syncthreads();
    if (t < B_) {
        int b = t;
        int total = 0;
        for (int s = 0; s < 7; s++) total += scnt[b][s];
        if (total < 1) total = 1;
        int sb = 0, snk = 0;
        for (int s = 0; s < 6; s++) {
            int cs = scnt[b][s];
            int nk = (int)ceilf((float)cs * 2048.0f / (float)total);  // f32 semantics
            if (nk > cs) nk = cs;
            offv[b * 6 + s] = snk;
            int need = 0;
            if (snk < K_) { need = K_ - snk; if (need > nk) need = nk; }
            n_needed[b * 6 + s] = need;
            sec_base[b * 6 + s] = sb;
            sb += cs; snk += nk;
        }
        s_total[b] = (snk < 1) ? 1 : snk;
    }
}

// ------------------------------------------------------------- compact ----
__global__ __launch_bounds__(CT)
void k_compact(const float* __restrict__ points, const int* __restrict__ sec_id,
               const int* __restrict__ sec_base, const int* __restrict__ bbase,
               int* __restrict__ comp_idx, float4* __restrict__ comp_xyz) {
    __shared__ int lc[4 * 6];
    __shared__ int sbase[6], blkb[6];
    int blk = blockIdx.x;
    int b = blk >> 8;                         // NBLK = 256 blocks per batch
    int tid = threadIdx.x, lane = tid & 63, wid = tid >> 6;
    if (tid < 6) sbase[tid] = sec_base[b * 6 + tid];
    else if (tid >= 64 && tid < 70) blkb[tid - 64] = bbase[blk * 6 + (tid - 64)];
    int gid = blk * CT + tid;
    int sec = sec_id[gid];
    unsigned long long mymask = 0;
    for (int s = 0; s < 6; s++) {
        unsigned long long m = __ballot(sec == s);
        if (sec == s) mymask = m;
        if (lane == 0) lc[wid * 6 + s] = __popcll(m);
    }
    __syncthreads();
    if (sec >= 0 && sec < 6) {
        int woff = 0;
        for (int w = 0; w < wid; w++) woff += lc[w * 6 + sec];
        int rank = __popcll(mymask & ((1ull << lane) - 1ull));
        int addr = b * N_ + sbase[sec] + blkb[sec] + woff + rank;
        const float* p = points + (size_t)gid * 3;
        comp_idx[addr] = gid & (N_ - 1);
        comp_xyz[addr] = make_float4(p[0], p[1], p[2], 0.0f);
    }
}

// ------------------------------------------- single-wave path (cs<=1024) ----
template<int R>
__device__ __forceinline__
void fps_wave(const float4* __restrict__ cxyz, float4* __restrict__ sxyz,
              int cs, int need, int base, int off, int* __restrict__ buf,
              int lane) {
    float px[R], py[R], pz[R], dmv[R];
    #pragma unroll
    for (int r = 0; r < R; r++) {
        int i = r * 64 + lane;
        if (i < cs) {
            float4 q = cxyz[i];
            sxyz[i] = q;
            px[r] = q.x; py[r] = q.y; pz[r] = q.z;
            dmv[r] = 1e10f;
        } else {
            px[r] = 0.0f; py[r] = 0.0f; pz[r] = 0.0f;
            dmv[r] = -1e30f;                 // pad: always loses
        }
    }
    if (lane == 0) buf[off] = base;
    if (need == 1) return;
    float4 f0 = cxyz[0];
    float lx = f0.x, ly = f0.y, lz = f0.z;

    #pragma unroll 1
    for (int k = 1; k < need; k++) {
        float bv = -1.0f; int bi = 0;
        #pragma unroll
        for (int r = 0; r < R; r++) {
            float dx = px[r] - lx, dy = py[r] - ly, dz = pz[r] - lz;
            float d = (dx*dx + dy*dy) + dz*dz;        // contract off
            float nd = fminf(dmv[r], d);
            dmv[r] = nd;
            if (nd > bv) { bv = nd; bi = r * 64 + lane; }
        }
        float mv = wave_max_f32_dpp(bv);
        float maxv = __int_as_float(__builtin_amdgcn_readlane(__float_as_int(mv), 63));
        unsigned idx = (bv == maxv) ? (unsigned)bi : 0xFFFFFFFFu;
        idx = wave_min_u32_dpp(idx);
        int wi = (int)(unsigned)__builtin_amdgcn_readlane((int)idx, 63);
        if (lane == 0) buf[off + k] = base + wi;
        float4 n4 = sxyz[wi];
        lx = n4.x; ly = n4.y; lz = n4.z;
    }
}

// ----------------------------------------------------------------- fps ----
// 4-wave scan + SPIN-POLL sync (no s_barrier in the pick loop):
// lane63 of each wave publishes a tagged record
//   rec = val<<32 | (pick_tag<<12) | (4095 - i)
// to its volatile LDS slot; all waves poll the 4 slots until every tag
// matches the current pick, then redundantly select the max (tag equal
// across slots -> u64 compare = (val, tie->min i)). Double-buffered parity;
// the poll of pick k's slots orders reuse at k+2 (a wave only reaches k+2
// after seeing every wave's k+1 record, which is written after that wave
// finished reading k). No barrier -> tid0's buf store queues in vmcnt with
// no drain; no writeback pass.
__global__ __launch_bounds__(FPS_T, 3)
void k_fps(const int* __restrict__ cnt, const int* __restrict__ sec_base,
           const int* __restrict__ offv, const int* __restrict__ n_needed,
           const float4* __restrict__ comp_xyz, int* __restrict__ buf) {
    __shared__ float4 sxyz[CAP];                    // 64 KB
    __shared__ unsigned long long slots[2][NW];
    int b = blockIdx.x / S_, s = blockIdx.x % S_;
    int need = n_needed[b * 6 + s];
    if (need <= 0) return;
    int cs = cnt[b * 8 + s];
    if (cs > CAP) return;                           // k_fps_big handles
    int base = b * N_ + sec_base[b * 6 + s];
    const float4* cxyz = comp_xyz + base;
    int off = b * K_ + offv[b * 6 + s];
    int tid = threadIdx.x, lane = tid & 63, wid = tid >> 6;

    if (cs <= SW_CAP) {
        // ---- barrier-free single wave; waves 1-3 exit ----
        if (wid != 0) return;
        if (cs <= 512) fps_wave< 8>(cxyz, sxyz, cs, need, base, off, buf, lane);
        else           fps_wave<16>(cxyz, sxyz, cs, need, base, off, buf, lane);
        return;
    }

    // ---- 4-wave poll path (1024 < cs <= 4096) ----
    float px[RMAX], py[RMAX], pz[RMAX], dmv[RMAX];
    #pragma unroll
    for (int r = 0; r < RMAX; r++) {
        int i = tid + r * FPS_T;
        if (r * FPS_T < cs && i < cs) {
            float4 q = cxyz[i];
            sxyz[i] = q;
            px[r] = q.x; py[r] = q.y; pz[r] = q.z;
            dmv[r] = 1e10f;
        }
    }
    if (tid < 2 * NW) ((unsigned long long*)slots)[tid] = 0xFFFFF000ull; // tag never matches
    if (tid == 0) buf[off] = base;
    __syncthreads();                                 // ONE barrier total
    if (need == 1) return;
    volatile unsigned long long* vslot = &slots[0][0];
    float4 l4 = sxyz[0];
    float lx = l4.x, ly = l4.y, lz = l4.z;

    #pragma unroll 1
    for (int k = 1; k < need; k++) {
        unsigned long long key = 0;
        #pragma unroll
        for (int r = 0; r < RMAX; r++) {
            int i = tid + r * FPS_T;
            if (r * FPS_T < cs && i < cs) {
                float dx = px[r] - lx, dy = py[r] - ly, dz = pz[r] - lz;
                float d = (dx*dx + dy*dy) + dz*dz;    // contract off
                float nd = fminf(dmv[r], d);
                dmv[r] = nd;
                unsigned long long kk =
                    ((unsigned long long)__float_as_uint(nd) << 32) | (unsigned)(~(unsigned)i);
                if (kk > key) key = kk;               // max val, tie -> min i
            }
        }
        key = wave_max_u64_dpp(key);
        int par = k & 1;
        unsigned tag = (unsigned)k;
        if (lane == 63) {
            unsigned val = (unsigned)(key >> 32);
            unsigned wi  = ~(unsigned)key;            // winner i of this wave
            unsigned long long rec = ((unsigned long long)val << 32)
                                   | (tag << 12) | (4095u - wi);
            vslot[par * NW + wid] = rec;              // volatile ds_write
        }
        unsigned long long r0, r1, r2, r3;
        do {
            r0 = vslot[par * NW + 0];
            r1 = vslot[par * NW + 1];
            r2 = vslot[par * NW + 2];
            r3 = vslot[par * NW + 3];
        } while (((unsigned)r0 >> 12) != tag || ((unsigned)r1 >> 12) != tag ||
                 ((unsigned)r2 >> 12) != tag || ((unsigned)r3 >> 12) != tag);
        unsigned long long bk = r0;
        if (r1 > bk) bk = r1;
        if (r2 > bk) bk = r2;
        if (r3 > bk) bk = r3;
        int bix = 4095 - (int)((unsigned)bk & 0xFFFu);
        if (tid == 0) buf[off + k] = base + bix;      // queued store, no drain
        float4 n4 = sxyz[bix];                        // uniform LDS broadcast
        lx = n4.x; ly = n4.y; lz = n4.z;
    }
}

// --------------------------------------- fps fallback (cs>4096, unlikely) ----
__global__ __launch_bounds__(256, 3)
void k_fps_big(const int* __restrict__ cnt, const int* __restrict__ sec_base,
               const int* __restrict__ offv, const int* __restrict__ n_needed,
               const float4* __restrict__ comp_xyz,
               float* __restrict__ dmin_g, int* __restrict__ buf) {
    __shared__ int pick[K_];
    __shared__ unsigned long long skey[2][4];
    int b = blockIdx.x / S_, s = blockIdx.x % S_;
    int need = n_needed[b * 6 + s];
    if (need <= 0) return;
    int cs = cnt[b * 8 + s];
    if (cs <= CAP) return;                   // k_fps handled
    int base = b * N_ + sec_base[b * 6 + s];
    const float4* cxyz = comp_xyz + base;
    int off = b * K_ + offv[b * 6 + s];
    int tid = threadIdx.x, lane = tid & 63, wid = tid >> 6;

    float* dm = dmin_g + base;
    if (tid == 0) pick[0] = 0;
    __syncthreads();
    float4 f0 = cxyz[0];
    float lx = f0.x, ly = f0.y, lz = f0.z;
    #pragma unroll 1
    for (int k = 1; k < need; k++) {
        unsigned long long key = 0;
        #pragma unroll 1
        for (int i = tid; i < cs; i += 256) {
            float4 q = cxyz[i];
            float dx = q.x - lx, dy = q.y - ly, dz = q.z - lz;
            float d = (dx*dx + dy*dy) + dz*dz;
            float prev = (k == 1) ? 1e10f : dm[i];
            float nd = fminf(prev, d);
            dm[i] = nd;
            unsigned long long kk =
                ((unsigned long long)__float_as_uint(nd) << 32) | (unsigned)(~(unsigned)i);
            if (kk > key) key = kk;
        }
        key = wave_max_u64_dpp(key);
        int par = k & 1;
        if (lane == 63) skey[par][wid] = key;
        __syncthreads();
        unsigned long long bk = skey[par][0];
        if (skey[par][1] > bk) bk = skey[par][1];
        if (skey[par][2] > bk) bk = skey[par][2];
        if (skey[par][3] > bk) bk = skey[par][3];
        int bix = (int)(~(unsigned)(bk & 0xFFFFFFFFull));
        if (tid == 0) pick[k] = bix;
        float4 n4 = cxyz[bix];
        lx = n4.x; ly = n4.y; lz = n4.z;
    }
    __syncthreads();
    #pragma unroll 1
    for (int i = tid; i < need; i += 256)
        buf[off + i] = base + pick[i];
}

// ----------------------------------------------------------------- out ----
__global__ void k_out(const float* __restrict__ points, const int* __restrict__ buf,
                      const int* __restrict__ comp_idx, const int* __restrict__ s_total,
                      float* __restrict__ out) {
    int i = blockIdx.x * 256 + threadIdx.x;
    if (i >= B_ * K_) return;
    int b = i / K_, j = i % K_;
    int st = s_total[b];
    int g = buf[b * K_ + (j % st)];          // compacted global slot
    int idx = comp_idx[g];                   // original point index
    const float* p = points + ((size_t)b * N_ + idx) * 3;
    float* o = out + (size_t)i * 3;
    o[0] = p[0]; o[1] = p[1]; o[2] = p[2];
}

// -------------------------------------------------------------- launch ----
extern "C" void kernel_launch(void* const* d_in, const int* in_sizes, int n_in,
                              void* d_out, int out_size, void* d_ws, size_t ws_size,
                              hipStream_t stream) {
    const float* points = (const float*)d_in[0];   // [B,N,3]
    const float* rois   = (const float*)d_in[1];   // [B,M,7]
    float* out = (float*)d_out;                    // [B,K,3]

    char* w = (char*)d_ws;
    auto carve = [&](size_t bytes) -> char* {
        char* p = w; w += (bytes + 255) & ~(size_t)255; return p;
    };
    int*    sec_id   = (int*)   carve((size_t)B_ * N_ * sizeof(int));
    int*    blkcnt   = (int*)   carve((size_t)B_ * NBLK * 8 * sizeof(int));
    int*    bbase    = (int*)   carve((size_t)B_ * NBLK * 6 * sizeof(int));
    int*    cnt      = (int*)   carve((size_t)B_ * 8 * sizeof(int));
    int*    offv     = (int*)   carve((size_t)B_ * 6 * sizeof(int));
    int*    n_needed = (int*)   carve((size_t)B_ * 6 * sizeof(int));
    int*    sec_base = (int*)   carve((size_t)B_ * 6 * sizeof(int));
    int*    s_total  = (int*)   carve((size_t)B_ * sizeof(int));
    int*    buf      = (int*)   carve((size_t)B_ * K_ * sizeof(int));
    int*    comp_idx = (int*)   carve((size_t)B_ * N_ * sizeof(int));
    float4* comp_xyz = (float4*)carve((size_t)B_ * N_ * sizeof(float4));
    float*  dmin_g   = (float*) carve((size_t)B_ * N_ * sizeof(float));

    hipLaunchKernelGGL(k_classify, dim3(B_ * NBLK), dim3(CT), 0, stream,
                       points, rois, sec_id, blkcnt);
    hipLaunchKernelGGL(k_plan, dim3(1), dim3(64), 0, stream,
                       blkcnt, bbase, cnt, offv, n_needed, sec_base, s_total);
    hipLaunchKernelGGL(k_compact, dim3(B_ * NBLK), dim3(CT), 0, stream,
                       points, sec_id, sec_base, bbase, comp_idx, comp_xyz);
    hipLaunchKernelGGL(k_fps, dim3(B_ * S_), dim3(FPS_T), 0, stream,
                       cnt, sec_base, offv, n_needed, comp_xyz, buf);
    hipLaunchKernelGGL(k_fps_big, dim3(B_ * S_), dim3(256), 0, stream,
                       cnt, sec_base, offv, n_needed, comp_xyz, dmin_g, buf);
    hipLaunchKernelGGL(k_out, dim3((B_ * K_ + 255) / 256), dim3(256), 0, stream,
                       points, buf, comp_idx, s_total, out);
}